// Round 6
// baseline (54.197 us; speedup 1.0000x reference)
//
#include <hip/hip_runtime.h>
#include <hip/hip_bf16.h>

#define NBINS 20
#define TPB 256
#define K 4   // float4 loads per stream per thread -> 16 elements/thread

// Max-MLP one-shot: each thread issues 8 independent global_load_dwordx4
// (4 conf + 4 acc = 8 KB/wave in flight), one wait, then 16 non-atomic
// LDS RMW updates into s[bin][tid] private columns (bank = tid%32, 2-way
// lane aliasing = free). bin = ceil((c-0.5)*40)-1 matches
// searchsorted(side='left')-1 (absmax 0.0, rounds 1-5); invalid samples
// (c<=0.5 or c>1) exec-masked off.
__global__ __launch_bounds__(TPB, 8) void ece_accum(
        const float4* __restrict__ confs,
        const float4* __restrict__ accs,
        int n4,                        // n/4
        float* __restrict__ partials,  // [NBINS][nb]
        int nb) {
    __shared__ float s[NBINS * TPB];
    const int t = threadIdx.x;
#pragma unroll
    for (int k = 0; k < NBINS; ++k) s[k * TPB + t] = 0.0f;
    __syncthreads();

    const int chunk = K * TPB;           // float4s per block per iteration
    const int nIter = n4 / chunk;        // 4096 for N=16.7M

    for (int it = blockIdx.x; it < nIter; it += gridDim.x) {
        const int base = it * chunk + t;
        float4 c[K], a[K];
#pragma unroll
        for (int k = 0; k < K; ++k) c[k] = confs[base + k * TPB];
#pragma unroll
        for (int k = 0; k < K; ++k) a[k] = accs[base + k * TPB];

#pragma unroll
        for (int k = 0; k < K; ++k) {
#pragma unroll
            for (int j = 0; j < 4; ++j) {
                float c1 = (j == 0) ? c[k].x : (j == 1) ? c[k].y : (j == 2) ? c[k].z : c[k].w;
                float a1 = (j == 0) ? a[k].x : (j == 1) ? a[k].y : (j == 2) ? a[k].z : a[k].w;
                float ft = __builtin_ceilf((c1 - 0.5f) * 40.0f);
                unsigned int bin = (unsigned int)((int)ft - 1);
                if (bin < (unsigned int)NBINS)
                    s[bin * TPB + t] += c1 - a1;
            }
        }
    }

    // tail (n4 not multiple of chunk) — handled by block 0, scalar float4s
    if (blockIdx.x == 0) {
        for (int i = nIter * chunk + t; i < n4; i += TPB) {
            float4 c4 = confs[i];
            float4 a4 = accs[i];
#pragma unroll
            for (int j = 0; j < 4; ++j) {
                float c1 = (j == 0) ? c4.x : (j == 1) ? c4.y : (j == 2) ? c4.z : c4.w;
                float a1 = (j == 0) ? a4.x : (j == 1) ? a4.y : (j == 2) ? a4.z : a4.w;
                float ft = __builtin_ceilf((c1 - 0.5f) * 40.0f);
                unsigned int bin = (unsigned int)((int)ft - 1);
                if (bin < (unsigned int)NBINS)
                    s[bin * TPB + t] += c1 - a1;
            }
        }
    }
    __syncthreads();

    // block reduce, reusing s[]
    float v[NBINS];
#pragma unroll
    for (int b = 0; b < NBINS; ++b) v[b] = s[b * TPB + t];
#pragma unroll
    for (int b = 0; b < NBINS; ++b) {
#pragma unroll
        for (int m = 32; m >= 1; m >>= 1) v[b] += __shfl_xor(v[b], m, 64);
    }
    __syncthreads();
    const int wave = t >> 6, lane = t & 63;
    if (lane == 0) {
#pragma unroll
        for (int b = 0; b < NBINS; ++b) s[b * 4 + wave] = v[b];
    }
    __syncthreads();
    if (t < NBINS) {
        float sum = s[t * 4 + 0] + s[t * 4 + 1] + s[t * 4 + 2] + s[t * 4 + 3];
        partials[t * nb + blockIdx.x] = sum;
    }
}

// One block: reduce nb partials per bin, ece = sum_b |S_b| / N
__global__ __launch_bounds__(512) void ece_final(
        const float* __restrict__ partials,
        float* __restrict__ out,
        float inv_n, int nb) {
    float s[NBINS];
#pragma unroll
    for (int b = 0; b < NBINS; ++b) s[b] = 0.0f;

    const int tid = threadIdx.x;
    const int nb4 = nb >> 2;
#pragma unroll
    for (int b = 0; b < NBINS; ++b) {
        const float4* pb = (const float4*)(partials + b * nb);
        for (int k = tid; k < nb4; k += blockDim.x) {
            float4 v = pb[k];
            s[b] += (v.x + v.y) + (v.z + v.w);
        }
    }
#pragma unroll
    for (int b = 0; b < NBINS; ++b) {
#pragma unroll
        for (int m = 32; m >= 1; m >>= 1)
            s[b] += __shfl_xor(s[b], m, 64);
    }

    __shared__ float red[NBINS][8];
    const int wave = tid >> 6;
    const int lane = tid & 63;
    if (lane == 0) {
#pragma unroll
        for (int b = 0; b < NBINS; ++b) red[b][wave] = s[b];
    }
    __syncthreads();

    if (tid == 0) {
        float ece = 0.0f;
#pragma unroll
        for (int b = 0; b < NBINS; ++b) {
            float tt = 0.0f;
#pragma unroll
            for (int w = 0; w < 8; ++w) tt += red[b][w];
            ece += fabsf(tt);
        }
        out[0] = ece * inv_n;
    }
}

extern "C" void kernel_launch(void* const* d_in, const int* in_sizes, int n_in,
                              void* d_out, int out_size, void* d_ws, size_t ws_size,
                              hipStream_t stream) {
    const float* confs = (const float*)d_in[0];
    const float* accs = (const float*)d_in[1];
    const int n = in_sizes[0];   // 16,777,216
    const int n4 = n / 4;

    // one iteration per block: nb = n4 / (K*TPB) = 4096, capped by ws
    int nb = n4 / (K * TPB);
    if (nb > 4096) nb = 4096;
    int ws_cap = (int)(ws_size / (NBINS * sizeof(float)));
    ws_cap &= ~3;
    if (nb > ws_cap) nb = ws_cap;
    if (nb < 4) nb = 4;

    float* partials = (float*)d_ws;

    ece_accum<<<nb, TPB, 0, stream>>>((const float4*)confs, (const float4*)accs,
                                      n4, partials, nb);
    ece_final<<<1, 512, 0, stream>>>(partials, (float*)d_out, 1.0f / (float)n, nb);
}